// Round 1
// baseline (1431.082 us; speedup 1.0000x reference)
//
#include <hip/hip_runtime.h>

// MaxPool 2x2, stride 2, fp32.
// Input : (16, 64, 512, 512)  = 268,435,456 floats (1.074 GB)
// Output: (16, 64, 256, 256)  =  67,108,864 floats (268 MB)
//
// Pure streaming (zero reuse): roofline = 1.342 GB / 6.3 TB/s ≈ 213 us.
//
// v2 changes vs v1 (one-thread-one-float4, 65536 blocks):
//  - grid-stride loop, 2048 blocks x 256 threads (8 blocks/CU): long-lived
//    waves, 32 iterations/thread, unroll x4 -> up to 16 dwordx4 loads in
//    flight per thread for latency hiding.
//  - nontemporal loads+stores: single-use stream, skip L2/L3 pollution.
//  - address math simplified: input offset = row*1024 + ow4*8
//    (bc*512*512 + 2*oh*512 == (bc*256+oh)*1024 == row*1024).

typedef float f4 __attribute__((ext_vector_type(4)));

#define BLOCK 256
#define GRID  2048   // 256 CUs * 8 blocks/CU

__global__ __launch_bounds__(BLOCK) void maxpool2x2_kernel(
    const float* __restrict__ in, float* __restrict__ out, int n_vec4)
{
    const int nthreads = GRID * BLOCK;                 // 524,288
    int t0 = blockIdx.x * BLOCK + threadIdx.x;

    #pragma unroll 4
    for (int t = t0; t < n_vec4; t += nthreads) {
        int ow4 = t & 63;          // which float4 within the output row
        int row = t >> 6;          // fused (bc*256 + oh) output-row index

        // input byte layout: row pair for output row `row` starts at
        // float offset row*1024; this thread's 8 input cols start +ow4*8.
        const float* base = in + ((size_t)row << 10) + (ow4 << 3);

        f4 a0 = __builtin_nontemporal_load((const f4*)(base));        // row 2*oh, cols 0-3
        f4 a1 = __builtin_nontemporal_load((const f4*)(base + 4));    // row 2*oh, cols 4-7
        f4 b0 = __builtin_nontemporal_load((const f4*)(base + 512));  // row 2*oh+1
        f4 b1 = __builtin_nontemporal_load((const f4*)(base + 516));

        f4 r;
        r.x = fmaxf(fmaxf(a0.x, a0.y), fmaxf(b0.x, b0.y));
        r.y = fmaxf(fmaxf(a0.z, a0.w), fmaxf(b0.z, b0.w));
        r.z = fmaxf(fmaxf(a1.x, a1.y), fmaxf(b1.x, b1.y));
        r.w = fmaxf(fmaxf(a1.z, a1.w), fmaxf(b1.z, b1.w));

        __builtin_nontemporal_store(r, (f4*)out + t);
    }
}

extern "C" void kernel_launch(void* const* d_in, const int* in_sizes, int n_in,
                              void* d_out, int out_size, void* d_ws, size_t ws_size,
                              hipStream_t stream) {
    const float* in = (const float*)d_in[0];
    float* out = (float*)d_out;

    int n_vec4 = out_size / 4;               // 16,777,216 output float4s

    maxpool2x2_kernel<<<GRID, BLOCK, 0, stream>>>(in, out, n_vec4);
}